// Round 1
// baseline (924.865 us; speedup 1.0000x reference)
//
#include <hip/hip_runtime.h>
#include <hip/hip_bf16.h>

// Problem constants (from reference)
#define N_TRIALS   8
#define T_TOTAL    600
#define N_NEURONS  30000
#define T_USE      500          // T_END - T_START
#define N_SAMPLES  50
#define MAX_COUNT  200
#define N_BINS     16
#define GROUP      8            // lanes per (s,t) output
#define EPS_D      1e-7

__constant__ int c_bins_unused[1]; // (placeholder, bins are a static array below)

__device__ __constant__ int BIN_SIZES[N_BINS] = {1,1,2,3,4,6,9,13,18,26,38,55,78,113,162,234};

// Kernel 1: sel[s*500+t] = sum_j mask[s][j] * spikes[trial_s][t][ids[s][j]]
// 8 lanes per (s,t); lane g handles id slots {g, g+8, ..., g+192}; skips mask==0 loads.
__global__ __launch_bounds__(256) void sel_kernel(
    const float* __restrict__ spikes,
    const int*   __restrict__ trials,
    const int*   __restrict__ ids,
    const float* __restrict__ mask,
    float*       __restrict__ sel)
{
    int u = blockIdx.x * 256 + threadIdx.x;
    const int total = N_SAMPLES * T_USE * GROUP;
    if (u >= total) return;
    int g = u & (GROUP - 1);
    int v = u >> 3;            // (s,t) linear index, 0..24999
    int t = v % T_USE;
    int s = v / T_USE;

    int trial = trials[s];
    const float* row = spikes + (size_t)trial * (T_TOTAL * N_NEURONS) + (size_t)t * N_NEURONS;
    const int*   sid = ids  + s * MAX_COUNT;
    const float* sm  = mask + s * MAX_COUNT;

    float acc = 0.f;
#pragma unroll
    for (int k = 0; k < MAX_COUNT / GROUP; ++k) {
        int j = g + (k << 3);
        float m = sm[j];
        if (m != 0.f) {
            acc += m * row[sid[j]];
        }
    }
    // reduce across the 8-lane group (contiguous lanes, same wave)
    acc += __shfl_xor(acc, 1);
    acc += __shfl_xor(acc, 2);
    acc += __shfl_xor(acc, 4);
    if (g == 0) sel[v] = acc;
}

// Kernel 2: single block. For each (bin, s): bin the 500-long sel row, compute
// population var/mean -> fano; average fanos over samples per bin; MSE vs
// experimental; out = 10 * mse.
__global__ __launch_bounds__(256) void fano_kernel(
    const float* __restrict__ sel,
    const float* __restrict__ expf,
    float*       __restrict__ out)
{
    __shared__ float fan[N_BINS * N_SAMPLES];   // 800 floats
    __shared__ double d2[N_BINS];

    int tid = threadIdx.x;
    for (int v = tid; v < N_BINS * N_SAMPLES; v += 256) {
        int bin = v / N_SAMPLES;
        int s   = v % N_SAMPLES;
        int bs  = BIN_SIZES[bin];
        int nb  = T_USE / bs;
        const float* rowp = sel + s * T_USE;
        double sum = 0.0, sumsq = 0.0;
        for (int b = 0; b < nb; ++b) {
            double c = 0.0;
            int base = b * bs;
            for (int q = 0; q < bs; ++q) c += (double)rowp[base + q];
            sum   += c;
            sumsq += c * c;
        }
        double mean = sum / nb;
        double var  = sumsq / nb - mean * mean;
        double m2   = mean < EPS_D ? EPS_D : mean;
        fan[v] = (float)(var / m2);
    }
    __syncthreads();

    if (tid < N_BINS) {
        double acc = 0.0;
        for (int s = 0; s < N_SAMPLES; ++s) acc += (double)fan[tid * N_SAMPLES + s];
        double fm   = acc / N_SAMPLES;
        double diff = (double)expf[tid] - fm;
        d2[tid] = diff * diff;
    }
    __syncthreads();

    if (tid == 0) {
        double mse = 0.0;
        for (int b = 0; b < N_BINS; ++b) mse += d2[b];
        mse /= N_BINS;
        out[0] = (float)(10.0 * mse);
    }
}

extern "C" void kernel_launch(void* const* d_in, const int* in_sizes, int n_in,
                              void* d_out, int out_size, void* d_ws, size_t ws_size,
                              hipStream_t stream)
{
    const float* spikes = (const float*)d_in[0];   // (8, 600, 30000) f32
    const float* expf   = (const float*)d_in[1];   // (16,) f32
    const int*   trials = (const int*)d_in[2];     // (50,) i32
    const int*   ids    = (const int*)d_in[3];     // (50, 200) i32
    const float* mask   = (const float*)d_in[4];   // (50, 200) f32
    float* out = (float*)d_out;

    float* sel = (float*)d_ws;                     // 50*500 floats = 100 KB

    const int total = N_SAMPLES * T_USE * GROUP;   // 200,000 threads
    int blocks = (total + 255) / 256;
    sel_kernel<<<blocks, 256, 0, stream>>>(spikes, trials, ids, mask, sel);
    fano_kernel<<<1, 256, 0, stream>>>(sel, expf, out);
}

// Round 2
// 685.472 us; speedup vs baseline: 1.3492x; 1.3492x over previous
//
#include <hip/hip_runtime.h>
#include <hip/hip_bf16.h>

// Problem constants (from reference)
#define N_TRIALS   8
#define T_TOTAL    600
#define N_NEURONS  30000
#define T_USE      500          // T_END - T_START
#define N_SAMPLES  50
#define MAX_COUNT  200
#define N_BINS     16
#define GROUP      8            // lanes per (s,t) output
#define EPS_D      1e-7

__device__ __constant__ int BIN_SIZES[N_BINS] = {1,1,2,3,4,6,9,13,18,26,38,55,78,113,162,234};

// Kernel 0: cnts[s] = sum(mask[s][:]) -- mask is a prefix mask (arange < count),
// so the count fully describes it. One wave per sample.
__global__ __launch_bounds__(256) void cnt_kernel(
    const float* __restrict__ mask, int* __restrict__ cnts)
{
    int w    = (blockIdx.x * 256 + threadIdx.x) >> 6;
    int lane = threadIdx.x & 63;
    if (w >= N_SAMPLES) return;
    const float* m = mask + w * MAX_COUNT;
    float sum = 0.f;
    for (int j = lane; j < MAX_COUNT; j += 64) sum += m[j];
    for (int k = 32; k; k >>= 1) sum += __shfl_xor(sum, k);
    if (lane == 0) cnts[w] = (int)(sum + 0.5f);
}

// Kernel 1: sel[s*500+t] = sum_{j<cnt_s} spikes[trial_s][t][ids[s][j]]
// 8 lanes per (s,t); branch-free loop -> all gathers independent & pipelined.
__global__ __launch_bounds__(256) void sel_kernel(
    const float* __restrict__ spikes,
    const int*   __restrict__ trials,
    const int*   __restrict__ ids,
    const int*   __restrict__ cnts,
    float*       __restrict__ sel)
{
    int u = blockIdx.x * 256 + threadIdx.x;
    int g = u & (GROUP - 1);
    int v = u >> 3;            // (s,t) linear index, 0..24999
    if (v >= N_SAMPLES * T_USE) return;
    int t = v % T_USE;
    int s = v / T_USE;

    int trial = trials[s];
    int cnt   = cnts[s];
    const float* row = spikes + (size_t)trial * (T_TOTAL * N_NEURONS)
                              + (size_t)t * N_NEURONS;
    const int*   sid = ids + s * MAX_COUNT;

    float acc = 0.f;
    for (int j = g; j < cnt; j += GROUP)
        acc += row[sid[j]];

    acc += __shfl_xor(acc, 1);
    acc += __shfl_xor(acc, 2);
    acc += __shfl_xor(acc, 4);
    if (g == 0) sel[v] = acc;
}

// Kernel 2: one wave per (bin, sample): bin the 500-long row, population
// var/mean -> fano[bin*50+s]. Lanes parallelize over the nb bins.
__global__ __launch_bounds__(256) void fano_stage(
    const float* __restrict__ sel,
    float*       __restrict__ fano)
{
    int w    = (blockIdx.x * 256 + threadIdx.x) >> 6;
    int lane = threadIdx.x & 63;
    if (w >= N_BINS * N_SAMPLES) return;
    int bin = w / N_SAMPLES;
    int s   = w % N_SAMPLES;
    int bs  = BIN_SIZES[bin];
    int nb  = T_USE / bs;
    const float* rowp = sel + s * T_USE;

    double sum = 0.0, sumsq = 0.0;
    for (int b = lane; b < nb; b += 64) {
        double c = 0.0;
        int base = b * bs;
        for (int q = 0; q < bs; ++q) c += (double)rowp[base + q];
        sum   += c;
        sumsq += c * c;
    }
    for (int k = 32; k; k >>= 1) {
        sum   += __shfl_xor(sum,   k);
        sumsq += __shfl_xor(sumsq, k);
    }
    if (lane == 0) {
        double mean = sum / nb;
        double var  = sumsq / nb - mean * mean;
        double m2   = mean < EPS_D ? EPS_D : mean;
        fano[w] = (float)(var / m2);
    }
}

// Kernel 3: fanos_mean per bin, MSE vs experimental, out = 10*mse. One wave.
__global__ void final_kernel(
    const float* __restrict__ fano,
    const float* __restrict__ expf,
    float*       __restrict__ out)
{
    int tid = threadIdx.x;   // 64 threads
    double d2 = 0.0;
    if (tid < N_BINS) {
        double acc = 0.0;
        for (int s = 0; s < N_SAMPLES; ++s) acc += (double)fano[tid * N_SAMPLES + s];
        double fm   = acc / N_SAMPLES;
        double diff = (double)expf[tid] - fm;
        d2 = diff * diff;
    }
    for (int k = 32; k; k >>= 1) d2 += __shfl_xor(d2, k);
    if (tid == 0) out[0] = (float)(10.0 * d2 / N_BINS);
}

extern "C" void kernel_launch(void* const* d_in, const int* in_sizes, int n_in,
                              void* d_out, int out_size, void* d_ws, size_t ws_size,
                              hipStream_t stream)
{
    const float* spikes = (const float*)d_in[0];   // (8, 600, 30000) f32
    const float* expf   = (const float*)d_in[1];   // (16,) f32
    const int*   trials = (const int*)d_in[2];     // (50,) i32
    const int*   ids    = (const int*)d_in[3];     // (50, 200) i32 (harness-converted)
    const float* mask   = (const float*)d_in[4];   // (50, 200) f32
    float* out = (float*)d_out;

    float* sel  = (float*)d_ws;                    // 25000 f32
    float* fano = sel + N_SAMPLES * T_USE;         // 800 f32
    int*   cnts = (int*)(fano + N_BINS * N_SAMPLES); // 50 i32

    cnt_kernel<<<(N_SAMPLES * 64 + 255) / 256, 256, 0, stream>>>(mask, cnts);

    const int total = N_SAMPLES * T_USE * GROUP;   // 200,000 threads
    sel_kernel<<<(total + 255) / 256, 256, 0, stream>>>(spikes, trials, ids, cnts, sel);

    fano_stage<<<(N_BINS * N_SAMPLES * 64 + 255) / 256, 256, 0, stream>>>(sel, fano);

    final_kernel<<<1, 64, 0, stream>>>(fano, expf, out);
}

// Round 3
// 679.844 us; speedup vs baseline: 1.3604x; 1.0083x over previous
//
#include <hip/hip_runtime.h>
#include <hip/hip_bf16.h>

// Problem constants (from reference)
#define N_TRIALS   8
#define T_TOTAL    600
#define N_NEURONS  30000
#define T_USE      500          // T_END - T_START
#define N_SAMPLES  50
#define MAX_COUNT  200
#define N_BINS     16
#define GROUP      16           // lanes per (s,t) output
#define EPS_D      1e-7

__device__ __constant__ int BIN_SIZES[N_BINS] = {1,1,2,3,4,6,9,13,18,26,38,55,78,113,162,234};

// Kernel 0: cnts[s] = sum(mask[s][:]) -- mask is a prefix mask (arange < count),
// so the count fully describes it. One wave per sample.
__global__ __launch_bounds__(256) void cnt_kernel(
    const float* __restrict__ mask, int* __restrict__ cnts)
{
    int w    = (blockIdx.x * 256 + threadIdx.x) >> 6;
    int lane = threadIdx.x & 63;
    if (w >= N_SAMPLES) return;
    const float* m = mask + w * MAX_COUNT;
    float sum = 0.f;
    for (int j = lane; j < MAX_COUNT; j += 64) sum += m[j];
    for (int k = 32; k; k >>= 1) sum += __shfl_xor(sum, k);
    if (lane == 0) cnts[w] = (int)(sum + 0.5f);
}

// Kernel 1: sel[s*500+t] = sum_{j<cnt_s} spikes[trial_s][t][ids[s][j]]
// 16 lanes per (s,t): 400K threads = ~25 waves/CU for latency hiding;
// branch-free loop, gathers independent & pipelined.
__global__ __launch_bounds__(256) void sel_kernel(
    const float* __restrict__ spikes,
    const int*   __restrict__ trials,
    const int*   __restrict__ ids,
    const int*   __restrict__ cnts,
    float*       __restrict__ sel)
{
    int u = blockIdx.x * 256 + threadIdx.x;
    int g = u & (GROUP - 1);
    int v = u >> 4;            // (s,t) linear index, 0..24999
    if (v >= N_SAMPLES * T_USE) return;
    int t = v % T_USE;
    int s = v / T_USE;

    int trial = trials[s];
    int cnt   = cnts[s];
    const float* row = spikes + (size_t)trial * (T_TOTAL * N_NEURONS)
                              + (size_t)t * N_NEURONS;
    const int*   sid = ids + s * MAX_COUNT;

    float acc = 0.f;
    for (int j = g; j < cnt; j += GROUP)
        acc += row[sid[j]];

    acc += __shfl_xor(acc, 1);
    acc += __shfl_xor(acc, 2);
    acc += __shfl_xor(acc, 4);
    acc += __shfl_xor(acc, 8);
    if (g == 0) sel[v] = acc;
}

// Kernel 2: one wave per (bin, sample): bin the 500-long row, population
// var/mean -> fano[bin*50+s]. Lanes parallelize over the nb bins.
__global__ __launch_bounds__(256) void fano_stage(
    const float* __restrict__ sel,
    float*       __restrict__ fano)
{
    int w    = (blockIdx.x * 256 + threadIdx.x) >> 6;
    int lane = threadIdx.x & 63;
    if (w >= N_BINS * N_SAMPLES) return;
    int bin = w / N_SAMPLES;
    int s   = w % N_SAMPLES;
    int bs  = BIN_SIZES[bin];
    int nb  = T_USE / bs;
    const float* rowp = sel + s * T_USE;

    double sum = 0.0, sumsq = 0.0;
    for (int b = lane; b < nb; b += 64) {
        double c = 0.0;
        int base = b * bs;
        for (int q = 0; q < bs; ++q) c += (double)rowp[base + q];
        sum   += c;
        sumsq += c * c;
    }
    for (int k = 32; k; k >>= 1) {
        sum   += __shfl_xor(sum,   k);
        sumsq += __shfl_xor(sumsq, k);
    }
    if (lane == 0) {
        double mean = sum / nb;
        double var  = sumsq / nb - mean * mean;
        double m2   = mean < EPS_D ? EPS_D : mean;
        fano[w] = (float)(var / m2);
    }
}

// Kernel 3: fanos_mean per bin, MSE vs experimental, out = 10*mse. One wave.
__global__ void final_kernel(
    const float* __restrict__ fano,
    const float* __restrict__ expf,
    float*       __restrict__ out)
{
    int tid = threadIdx.x;   // 64 threads
    double d2 = 0.0;
    if (tid < N_BINS) {
        double acc = 0.0;
        for (int s = 0; s < N_SAMPLES; ++s) acc += (double)fano[tid * N_SAMPLES + s];
        double fm   = acc / N_SAMPLES;
        double diff = (double)expf[tid] - fm;
        d2 = diff * diff;
    }
    for (int k = 32; k; k >>= 1) d2 += __shfl_xor(d2, k);
    if (tid == 0) out[0] = (float)(10.0 * d2 / N_BINS);
}

extern "C" void kernel_launch(void* const* d_in, const int* in_sizes, int n_in,
                              void* d_out, int out_size, void* d_ws, size_t ws_size,
                              hipStream_t stream)
{
    const float* spikes = (const float*)d_in[0];   // (8, 600, 30000) f32
    const float* expf   = (const float*)d_in[1];   // (16,) f32
    const int*   trials = (const int*)d_in[2];     // (50,) i32
    const int*   ids    = (const int*)d_in[3];     // (50, 200) i32 (harness-converted)
    const float* mask   = (const float*)d_in[4];   // (50, 200) f32
    float* out = (float*)d_out;

    float* sel  = (float*)d_ws;                    // 25000 f32
    float* fano = sel + N_SAMPLES * T_USE;         // 800 f32
    int*   cnts = (int*)(fano + N_BINS * N_SAMPLES); // 50 i32

    cnt_kernel<<<(N_SAMPLES * 64 + 255) / 256, 256, 0, stream>>>(mask, cnts);

    const int total = N_SAMPLES * T_USE * GROUP;   // 400,000 threads
    sel_kernel<<<(total + 255) / 256, 256, 0, stream>>>(spikes, trials, ids, cnts, sel);

    fano_stage<<<(N_BINS * N_SAMPLES * 64 + 255) / 256, 256, 0, stream>>>(sel, fano);

    final_kernel<<<1, 64, 0, stream>>>(fano, expf, out);
}